// Round 6
// baseline (74.398 us; speedup 1.0000x reference)
//
#include <hip/hip_runtime.h>
#include <math.h>

// S4D diagonal SSM kernel generation (ZOH, real_type='exp', rep=1)
// K[h,l] = sum_n Re( G[h,n] * w[h,n]^l ),  w = exp(dt*A),  G = 2*B*C*(w-1)/A.
//
// Round-6: occupancy x2 (R4/R5 proved instruction count & barriers are not
// the limiter; R1's VALUBusy=47.7% @1.5 waves/SIMD showed ~32% per-wave
// issue duty -> latency-bound):
//  - grid = 1536 = 768 h x 2 l-halves; block = 256 threads (4 waves).
//    __launch_bounds__(256,6) -> VGPR cap ~84, LDS 18 KB/block ->
//    EXACTLY 6 blocks/CU resident, 24 waves/CU = 6 waves/SIMD (was 3).
//  - LCH=16 (acc2[16] = 32 VGPR) keeps live set ~75 regs under the cap
//    (R2 lesson: cap 64 with ~96 live = scratch-spill disaster; margin here).
//  - seeds u = w^(16*(64*half+tl)) via polar HW transcendentals
//    (v_fract/v_sin/v_cos revolutions-native, v_exp2); phase(w^16) reduced
//    mod 1 rev in double at setup.
//  - inner: 4 independent pair-packed order-2 real recurrence chains
//    r_{l+1} = 2Re(w) r_l - |w|^2 r_{l-1} (v_pk_mul/fma/add).
//  - 2-buffer / 3-barrier LDS tree reduction (16 KB), [j][tl] stride-1.

typedef float v2f __attribute__((ext_vector_type(2)));

#define H_DIM 768
#define N_DIM 64
#define L_DIM 2048
#define TPB   256
#define LTH   64   // l-threads per block
#define LCH   16   // l per thread

__global__ __launch_bounds__(TPB, 6) void s4d_gen_kernel(
    const float* __restrict__ log_dt,
    const float* __restrict__ B_ri,
    const float* __restrict__ inv_A_real,
    const float* __restrict__ A_imag,
    const float* __restrict__ C_ri,
    float* __restrict__ out)
{
    __shared__ float4 sP0[N_DIM];           // {revs(w^16) mod 1, log2|w^16|, Gr, Gi}
    __shared__ float4 sP1[N_DIM];           // {Gwr, Gwi, 2Re(w), -|w|^2}
    __shared__ v2f    sRedV[2][LCH][LTH];   // packed partials (2-buffer)

    const int h    = blockIdx.x >> 1;
    const int half = blockIdx.x & 1;
    const int t    = threadIdx.x;
    const int nb   = t >> 6;   // n-group 0..3 (wave-uniform)
    const int tl   = t & 63;   // l-chunk within this half

    // ---- setup: one thread per n (duplicated across the 2 half-blocks) ----
    if (t < N_DIM) {
        const int n   = t;
        const int idx = h * N_DIM + n;
        const float dt = expf(log_dt[h]);
        const float Ar = -expf(inv_A_real[idx]);
        const float Ai = A_imag[idx];
        const float dtAr = Ar * dt;
        const float dtAi = Ai * dt;
        const float e  = expf(dtAr);
        float s, c;
        sincosf(dtAi, &s, &c);
        const float wr = e * c, wi = e * s;
        const float inv = 1.0f / (Ar * Ar + Ai * Ai);
        const float nr = wr - 1.0f, ni = wi;
        const float qr = (nr * Ar + ni * Ai) * inv;
        const float qi = (ni * Ar - nr * Ai) * inv;
        const float Br = B_ri[2 * idx], Bi = B_ri[2 * idx + 1];
        const float Cr = C_ri[2 * idx], Ci = C_ri[2 * idx + 1];
        const float BCr = Br * Cr - Bi * Ci;
        const float BCi = Br * Ci + Bi * Cr;
        const float Gr = 2.0f * (BCr * qr - BCi * qi);
        const float Gi = 2.0f * (BCr * qi + BCi * qr);
        // phase of w^16 in revolutions, reduced mod 1 in double (setup-only)
        const double revs16 = (double)dtAi * (16.0 / (2.0 * M_PI));
        const float  r16f   = (float)(revs16 - floor(revs16));
        const float  l2m16  = dtAr * (16.0f * 1.4426950408889634f);
        sP0[n] = make_float4(r16f, l2m16, Gr, Gi);
        sP1[n] = make_float4(Gr * wr - Gi * wi, Gr * wi + Gi * wr,
                             2.0f * wr, -(wr * wr + wi * wi));
    }
    __syncthreads();

    v2f acc2[LCH];
    #pragma unroll
    for (int j = 0; j < LCH; ++j) acc2[j] = (v2f){0.0f, 0.0f};

    const int   nbase = nb * 16;
    const float ef    = (float)(half * 64 + tl);   // exponent in units of w^16

    #pragma unroll
    for (int hf = 0; hf < 2; ++hf) {
        const int n0 = nbase + hf * 8;

        // ---- init: 8 n, polar u = w^(16 ef); seeds s0=Re(Gu), s1=Re(Gwu) ----
        v2f S0[4], S1[4], C1[4], NC2[4];
        #pragma unroll
        for (int p = 0; p < 4; ++p) {
            const float4 pa = sP0[n0 + 2 * p],     pb = sP0[n0 + 2 * p + 1];
            const float4 qa = sP1[n0 + 2 * p],     qb = sP1[n0 + 2 * p + 1];
            const float fa = __builtin_amdgcn_fractf(pa.x * ef);
            const float fb = __builtin_amdgcn_fractf(pb.x * ef);
            const float ma = __builtin_amdgcn_exp2f(pa.y * ef);
            const float mb = __builtin_amdgcn_exp2f(pb.y * ef);
            const float ca = __builtin_amdgcn_cosf(fa), sa = __builtin_amdgcn_sinf(fa);
            const float cb = __builtin_amdgcn_cosf(fb), sb = __builtin_amdgcn_sinf(fb);
            const float ura = ma * ca, uia = ma * sa;
            const float urb = mb * cb, uib = mb * sb;
            S0[p]  = (v2f){fmaf(pa.z, ura, -(pa.w * uia)),
                           fmaf(pb.z, urb, -(pb.w * uib))};
            S1[p]  = (v2f){fmaf(qa.x, ura, -(qa.y * uia)),
                           fmaf(qb.x, urb, -(qb.y * uib))};
            C1[p]  = (v2f){qa.z, qb.z};
            NC2[p] = (v2f){qa.w, qb.w};
        }

        // ---- inner: 4 independent pair-packed order-2 recurrence chains ----
        #pragma unroll
        for (int j = 0; j < LCH; ++j) {
            const v2f t1 = S0[0] + S0[1];
            const v2f t2 = S0[2] + S0[3];
            acc2[j] += t1;
            acc2[j] += t2;
            #pragma unroll
            for (int k = 0; k < 4; ++k) {
                v2f tt = C1[k] * S1[k];                                // v_pk_mul_f32
                v2f nn = __builtin_elementwise_fma(NC2[k], S0[k], tt); // v_pk_fma_f32
                S0[k] = S1[k]; S1[k] = nn;
            }
        }
    }

    // ---- 2-buffer / 3-barrier tree reduction over the 4 n-groups ----
    if (nb >= 2) {
        #pragma unroll
        for (int j = 0; j < LCH; ++j) sRedV[nb - 2][j][tl] = acc2[j];
    }
    __syncthreads();
    if (nb < 2) {
        #pragma unroll
        for (int j = 0; j < LCH; ++j) acc2[j] += sRedV[nb][j][tl];
    }
    __syncthreads();
    if (nb == 1) {
        #pragma unroll
        for (int j = 0; j < LCH; ++j) sRedV[0][j][tl] = acc2[j];
    }
    __syncthreads();
    if (nb == 0) {
        #pragma unroll
        for (int j = 0; j < LCH; ++j) acc2[j] += sRedV[0][j][tl];
        float acc[LCH];
        #pragma unroll
        for (int j = 0; j < LCH; ++j) acc[j] = acc2[j].x + acc2[j].y;
        float* op = out + (size_t)h * L_DIM + half * (L_DIM / 2) + tl * LCH;
        #pragma unroll
        for (int j = 0; j < LCH; j += 4) {
            *reinterpret_cast<float4*>(op + j) =
                make_float4(acc[j], acc[j + 1], acc[j + 2], acc[j + 3]);
        }
    }
}

extern "C" void kernel_launch(void* const* d_in, const int* in_sizes, int n_in,
                              void* d_out, int out_size, void* d_ws, size_t ws_size,
                              hipStream_t stream) {
    const float* log_dt     = (const float*)d_in[0];
    const float* B_ri       = (const float*)d_in[1];
    const float* inv_A_real = (const float*)d_in[2];
    const float* A_imag     = (const float*)d_in[3];
    const float* C_ri       = (const float*)d_in[4];
    float* out = (float*)d_out;
    hipLaunchKernelGGL(s4d_gen_kernel, dim3(H_DIM * 2), dim3(TPB), 0, stream,
                       log_dt, B_ri, inv_A_real, A_imag, C_ri, out);
}